// Round 2
// baseline (1896.571 us; speedup 1.0000x reference)
//
#include <hip/hip_runtime.h>

// InteractionNetwork — fused MFMA, transposed-product formulation.
// OUT^T = W^T * X^T per layer: weight frags persistent in VGPRs (A-operand),
// activation frags read row-major from swizzled LDS (B-operand), outputs land
// as 4 consecutive cols of one row -> ds_write_b64. 58KB LDS -> 2 blocks/CU.

#define NNODES 50000
#define NEDGES 800000
#define NBLK 512

typedef __bf16 bf16x8 __attribute__((ext_vector_type(8)));
typedef float f32x4 __attribute__((ext_vector_type(4)));
#define MFMA(a, b, c) __builtin_amdgcn_mfma_f32_16x16x32_bf16(a, b, c, 0, 0, 0)

// LDS map (bytes)
#define OFF_A 0       // [64 rows][192 bf16] stride 384, XOR-swizzled; [0,256) reused as H1; [256,384) = residual seg
#define OFF_H0 24576  // [64 rows][128 bf16] stride 256, XOR-swizzled
#define OFF_SA 40960  // DMA strip: 16 chunks x (1024B data + 16B pad) = 16640
#define OFF_P 57600   // [64 rows][4 float2] partial (s,ss) = 2048
#define OFF_IX 59648  // [64] int dst indices = 256
#define SMEM 59904

__device__ __forceinline__ unsigned short f2bf(float f) {
  unsigned u = __builtin_bit_cast(unsigned, f);
  u = (u + 0x7fffu + ((u >> 16) & 1u)) >> 16;
  return (unsigned short)u;
}
__device__ __forceinline__ float bf2f(unsigned short h) {
  return __builtin_bit_cast(float, (unsigned)h << 16);
}
__device__ __forceinline__ unsigned long long pk4(f32x4 v) {
  union { unsigned short h[4]; unsigned long long u; } p;
  p.h[0] = f2bf(v[0]); p.h[1] = f2bf(v[1]); p.h[2] = f2bf(v[2]); p.h[3] = f2bf(v[3]);
  return p.u;
}
__device__ __forceinline__ void cvt8s(float4 f0, float4 f1, char* d) {
  union { unsigned short us[8]; int4 v; } u;
  u.us[0] = f2bf(f0.x); u.us[1] = f2bf(f0.y); u.us[2] = f2bf(f0.z); u.us[3] = f2bf(f0.w);
  u.us[4] = f2bf(f1.x); u.us[5] = f2bf(f1.y); u.us[6] = f2bf(f1.z); u.us[7] = f2bf(f1.w);
  *(int4*)d = u.v;
}

// EDGE: A = [x[dst] | x[src] | attr(DMA)], resid = attr, atomics into agg.
// NODE: A = [aggm | aggw | x(DMA)],       resid = x (seg2 too), no atomics.
//       (node W0 rows are pre-rotated by prep_w so concat order matches.)
template <bool EDGE>
__global__ __launch_bounds__(512, 4) void mlp_block(
    const float* __restrict__ g1, const float* __restrict__ g2,
    const float* __restrict__ g3, const int* __restrict__ srcI,
    const int* __restrict__ dstI, const unsigned short* __restrict__ Wt,
    const float* __restrict__ b0, const float* __restrict__ b1,
    const float* __restrict__ b2, const float* __restrict__ gam,
    const float* __restrict__ bet, float* __restrict__ outp,
    float* __restrict__ agg, int M) {
  __shared__ __align__(16) char sm[SMEM];
  const int tid = threadIdx.x, lane = tid & 63, wave = tid >> 6;
  const int lrow = lane & 15, cg = lane >> 4;
  const unsigned short* Wt0 = Wt;
  const unsigned short* Wt1 = Wt + 24576;
  const unsigned short* Wt2 = Wt + 40960;
  const int ntiles = (M + 63) >> 6;

  // wave roles: L0: cols (cg2*2..+1 coltiles of 8), rows rg half; L1: ct=wave; L2: ct2=cg2, rows rg half
  const int cg2 = wave & 3, rg = wave >> 2, ctb = cg2 * 2;

  // ---- persistent weight fragments (A-operand = W^T rows = out-cols) ----
  bf16x8 w0f[2][6], w1f[4], w2f[4];
#pragma unroll
  for (int i = 0; i < 2; ++i)
#pragma unroll
    for (int kk = 0; kk < 6; ++kk)
      w0f[i][kk] = *(const bf16x8*)(Wt0 + ((ctb + i) * 16 + lrow) * 192 + kk * 32 + cg * 8);
#pragma unroll
  for (int kk = 0; kk < 4; ++kk)
    w1f[kk] = *(const bf16x8*)(Wt1 + (wave * 16 + lrow) * 128 + kk * 32 + cg * 8);
#pragma unroll
  for (int kk = 0; kk < 4; ++kk)
    w2f[kk] = *(const bf16x8*)(Wt2 + (cg2 * 16 + lrow) * 128 + kk * 32 + cg * 8);

  // staging map: thread covers row = (tid>>5)*4 + ((tid&31)>>3), float-octet oct = tid&7
  const int srow = (tid >> 5) * 4 + ((tid & 31) >> 3), oct = tid & 7;

  int t = blockIdx.x;
  if (t >= ntiles) return;

  // ---- prologue: prefetch tile t ----
  float4 ga0, ga1, gb0, gb1;
  int dcur = 0;
  {
    int row = t * 64 + srow;
    int r1, r2;
    if (EDGE) { dcur = dstI[row]; r1 = dcur; r2 = srcI[row]; }
    else { int rr = min(row, M - 1); r1 = rr; r2 = rr; }
    const float* p1 = g1 + (size_t)r1 * 64 + oct * 8;
    const float* p2 = g2 + (size_t)r2 * 64 + oct * 8;
    ga0 = *(const float4*)p1; ga1 = *(const float4*)(p1 + 4);
    gb0 = *(const float4*)p2; gb1 = *(const float4*)(p2 + 4);
#pragma unroll
    for (int i = 0; i < 2; ++i) {  // DMA seg2 strip
      int chunk = wave * 2 + i;
      const float* gsrc;
      if (EDGE) gsrc = g3 + (size_t)t * 4096 + chunk * 256 + lane * 4;
      else { int gr = min(t * 64 + chunk * 4 + (lane >> 4), M - 1); gsrc = g3 + (size_t)gr * 64 + (lane & 15) * 4; }
      __builtin_amdgcn_global_load_lds((const __attribute__((address_space(1))) unsigned int*)gsrc,
          (__attribute__((address_space(3))) unsigned int*)(sm + OFF_SA + chunk * 1040), 16, 0, 0);
    }
  }

  for (; t < ntiles; t += NBLK) {
    const int tn = t + NBLK;
    const bool more = tn < ntiles;
    __syncthreads();  // (a) strips+A free; DMA(t) drained
    // ---------------- W: regs + strip -> bf16 A tile ----------------
    {
      char* a0 = sm + OFF_A + srow * 384;
      const int swz = (srow & 7) << 4;
      cvt8s(ga0, ga1, a0 + ((oct * 16) ^ swz));
      cvt8s(gb0, gb1, a0 + ((128 + oct * 16) ^ swz));
      const char* sa = sm + OFF_SA + (srow >> 2) * 1040 + (srow & 3) * 256 + oct * 32;
      float4 c0 = *(const float4*)sa, c1 = *(const float4*)(sa + 16);
      cvt8s(c0, c1, a0 + ((256 + oct * 16) ^ swz));
      if (EDGE && (tid & 7) == 0) ((int*)(sm + OFF_IX))[srow] = dcur;
    }
    int dn = 0, sn = 0;
    if (EDGE && more) { int row = tn * 64 + srow; dn = dstI[row]; sn = srcI[row]; }
    __syncthreads();  // (b) A ready
    // ---------------- P: issue prefetch for tn ----------------
    if (more) {
      const float *p1, *p2;
      if (EDGE) {
        p1 = g1 + (size_t)dn * 64 + oct * 8;
        p2 = g2 + (size_t)sn * 64 + oct * 8;
        dcur = dn;
      } else {
        int rr = min(tn * 64 + srow, M - 1);
        p1 = g1 + (size_t)rr * 64 + oct * 8;
        p2 = g2 + (size_t)rr * 64 + oct * 8;
      }
      ga0 = *(const float4*)p1; ga1 = *(const float4*)(p1 + 4);
      gb0 = *(const float4*)p2; gb1 = *(const float4*)(p2 + 4);
#pragma unroll
      for (int i = 0; i < 2; ++i) {
        int chunk = wave * 2 + i;
        const float* gsrc;
        if (EDGE) gsrc = g3 + (size_t)tn * 4096 + chunk * 256 + lane * 4;
        else { int gr = min(tn * 64 + chunk * 4 + (lane >> 4), M - 1); gsrc = g3 + (size_t)gr * 64 + (lane & 15) * 4; }
        __builtin_amdgcn_global_load_lds((const __attribute__((address_space(1))) unsigned int*)gsrc,
            (__attribute__((address_space(3))) unsigned int*)(sm + OFF_SA + chunk * 1040), 16, 0, 0);
      }
    }
    // ---------------- L0: A[192] -> H0[128], relu ----------------
#pragma unroll
    for (int j = 0; j < 2; ++j) {
      const int rt = rg * 2 + j, row = rt * 16 + lrow, swz = (row & 7) << 4;
      const char* ab = sm + OFF_A + row * 384;
      f32x4 acc0 = {0.f, 0.f, 0.f, 0.f}, acc1 = {0.f, 0.f, 0.f, 0.f};
#pragma unroll
      for (int kk = 0; kk < 6; ++kk) {
        bf16x8 bf = *(const bf16x8*)(ab + ((kk * 64 + cg * 16) ^ swz));
        acc0 = MFMA(w0f[0][kk], bf, acc0);
        acc1 = MFMA(w0f[1][kk], bf, acc1);
      }
#pragma unroll
      for (int i = 0; i < 2; ++i) {
        f32x4 acc = i ? acc1 : acc0;
        const int col = (ctb + i) * 16 + cg * 4;
        f32x4 bb = *(const f32x4*)(b0 + col);
        f32x4 h;
#pragma unroll
        for (int q = 0; q < 4; ++q) h[q] = fmaxf(acc[q] + bb[q], 0.f);
        *(unsigned long long*)(sm + OFF_H0 + row * 256 + (((ctb + i) * 32 + cg * 8) ^ swz)) = pk4(h);
      }
    }
    __syncthreads();  // (c) H0 ready
    // ---------------- L1: H0 -> H1 (A[0,256) overlay), relu ----------------
#pragma unroll
    for (int rt = 0; rt < 4; ++rt) {
      const int row = rt * 16 + lrow, swz = (row & 7) << 4;
      const char* hb = sm + OFF_H0 + row * 256;
      f32x4 acc = {0.f, 0.f, 0.f, 0.f};
#pragma unroll
      for (int kk = 0; kk < 4; ++kk)
        acc = MFMA(w1f[kk], *(const bf16x8*)(hb + ((kk * 64 + cg * 16) ^ swz)), acc);
      const int col = wave * 16 + cg * 4;
      f32x4 bb = *(const f32x4*)(b1 + col);
      f32x4 h;
#pragma unroll
      for (int q = 0; q < 4; ++q) h[q] = fmaxf(acc[q] + bb[q], 0.f);
      *(unsigned long long*)(sm + OFF_A + row * 384 + ((wave * 32 + cg * 8) ^ swz)) = pk4(h);
    }
    __syncthreads();  // (d) H1 ready
    // ---------------- L2p: H1 -> acc + bias, LN partials ----------------
    f32x4 accE[2];
#pragma unroll
    for (int j = 0; j < 2; ++j) {
      const int rt = rg * 2 + j, row = rt * 16 + lrow, swz = (row & 7) << 4;
      const char* hb = sm + OFF_A + row * 384;
      f32x4 acc = {0.f, 0.f, 0.f, 0.f};
#pragma unroll
      for (int kk = 0; kk < 4; ++kk)
        acc = MFMA(w2f[kk], *(const bf16x8*)(hb + ((kk * 64 + cg * 16) ^ swz)), acc);
      f32x4 bb = *(const f32x4*)(b2 + cg2 * 16 + cg * 4);
#pragma unroll
      for (int q = 0; q < 4; ++q) acc[q] += bb[q];
      float s = acc[0] + acc[1] + acc[2] + acc[3];
      float ss = acc[0] * acc[0] + acc[1] * acc[1] + acc[2] * acc[2] + acc[3] * acc[3];
      s += __shfl_xor(s, 16, 64); s += __shfl_xor(s, 32, 64);
      ss += __shfl_xor(ss, 16, 64); ss += __shfl_xor(ss, 32, 64);
      if (cg == 0) *(float2*)(sm + OFF_P + row * 32 + cg2 * 8) = make_float2(s, ss);
      accE[j] = acc;
    }
    __syncthreads();  // (e) partials ready
    // ---------------- E2: LN + residual + store (+atomics) ----------------
#pragma unroll
    for (int j = 0; j < 2; ++j) {
      const int rt = rg * 2 + j, row = rt * 16 + lrow, gr = t * 64 + row;
      if (!EDGE && gr >= M) continue;
      float4 p0 = *(const float4*)(sm + OFF_P + row * 32);
      float4 p1 = *(const float4*)(sm + OFF_P + row * 32 + 16);
      float s = p0.x + p0.z + p1.x + p1.z, ss = p0.y + p0.w + p1.y + p1.w;
      float mean = s * (1.f / 64.f);
      float var = fmaxf(ss * (1.f / 64.f) - mean * mean, 0.f);
      float inv = rsqrtf(var + 1e-5f);
      const int col = cg2 * 16 + cg * 4, swz = (row & 7) << 4;
      f32x4 gv = *(const f32x4*)(gam + col), bv = *(const f32x4*)(bet + col);
      unsigned long long rv =
          *(const unsigned long long*)(sm + OFF_A + row * 384 + ((256 + cg2 * 32 + cg * 8) ^ swz));
      f32x4 a = accE[j];
      f32x4 o;
      o[0] = (a[0] - mean) * inv * gv[0] + bv[0] + bf2f((unsigned short)rv);
      o[1] = (a[1] - mean) * inv * gv[1] + bv[1] + bf2f((unsigned short)(rv >> 16));
      o[2] = (a[2] - mean) * inv * gv[2] + bv[2] + bf2f((unsigned short)(rv >> 32));
      o[3] = (a[3] - mean) * inv * gv[3] + bv[3] + bf2f((unsigned short)(rv >> 48));
      *(f32x4*)(outp + (size_t)gr * 64 + col) = o;
      if (EDGE) {
        int d = ((const int*)(sm + OFF_IX))[row];
        float* ap = agg + (size_t)d * 64 + col;
        atomicAdd(ap, o[0]); atomicAdd(ap + 1, o[1]);
        atomicAdd(ap + 2, o[2]); atomicAdd(ap + 3, o[3]);
      }
    }
  }
}

// ---- prep: transpose+cast weights to bf16 [out][in]; rotate upd-W0 rows by 64
//      (node concat stored as [aggm|aggw|x] so x lands in the DMA segment) ----
struct PrepArgs { const float* w[9]; unsigned short* wt[3]; };

__global__ void prep_w(PrepArgs pa) {
  int i = blockIdx.x * 256 + threadIdx.x;
  if (i >= 3 * 49152) return;
  int mlp = i / 49152;
  int rem = i - mlp * 49152;
  int mat, off, K, N;
  if (rem < 24576)      { mat = 0; off = 0;     K = 192; N = 128; }
  else if (rem < 40960) { mat = 1; off = 24576; K = 128; N = 128; }
  else                  { mat = 2; off = 40960; K = 128; N = 64;  }
  int local = rem - off;
  int n = local / K, k = local - n * K;
  if (mlp == 2 && mat == 0) k = (k + 64) % 192;  // concat rotation for node MLP
  pa.wt[mlp][rem] = f2bf(pa.w[mlp * 3 + mat][k * N + n]);
}

__global__ void zero_f4(float4* p, int n) {
  int i = blockIdx.x * blockDim.x + threadIdx.x;
  if (i < n) p[i] = make_float4(0.f, 0.f, 0.f, 0.f);
}

extern "C" void kernel_launch(void* const* d_in, const int* in_sizes, int n_in,
                              void* d_out, int out_size, void* d_ws, size_t ws_size,
                              hipStream_t stream) {
  const float* x      = (const float*)d_in[0];
  const int*   meIdx  = (const int*)d_in[1];
  const float* meAttr = (const float*)d_in[2];
  const int*   weIdx  = (const int*)d_in[3];
  const float* weAttr = (const float*)d_in[4];

  float* out_x  = (float*)d_out;
  float* out_em = out_x + (size_t)NNODES * 64;
  float* out_ew = out_em + (size_t)NEDGES * 64;

  char* ws = (char*)d_ws;
  unsigned short* WtM = (unsigned short*)ws;
  unsigned short* WtW = (unsigned short*)(ws + 98304);
  unsigned short* WtU = (unsigned short*)(ws + 196608);
  float* aggm = (float*)(ws + 294912);
  float* aggw = aggm + (size_t)NNODES * 64;

  zero_f4<<<dim3(6250), dim3(256), 0, stream>>>((float4*)aggm, 1600000);

  PrepArgs pa;
  for (int m = 0; m < 3; ++m)
    for (int l = 0; l < 3; ++l)
      pa.w[m * 3 + l] = (const float*)d_in[5 + m * 8 + l * 2];
  pa.wt[0] = WtM; pa.wt[1] = WtW; pa.wt[2] = WtU;
  prep_w<<<dim3(576), dim3(256), 0, stream>>>(pa);

  // mesh edges: src = row0, dst = row1; x_i = x[dst], x_j = x[src]
  mlp_block<true><<<dim3(NBLK), dim3(512), 0, stream>>>(
      x, x, meAttr, meIdx, meIdx + NEDGES, WtM,
      (const float*)d_in[6], (const float*)d_in[8], (const float*)d_in[10],
      (const float*)d_in[11], (const float*)d_in[12],
      out_em, aggm, NEDGES);
  // world edges
  mlp_block<true><<<dim3(NBLK), dim3(512), 0, stream>>>(
      x, x, weAttr, weIdx, weIdx + NEDGES, WtW,
      (const float*)d_in[14], (const float*)d_in[16], (const float*)d_in[18],
      (const float*)d_in[19], (const float*)d_in[20],
      out_ew, aggw, NEDGES);
  // node update: A = [aggm | aggw | x], residual = x
  mlp_block<false><<<dim3(NBLK), dim3(512), 0, stream>>>(
      aggm, aggw, x, nullptr, nullptr, WtU,
      (const float*)d_in[22], (const float*)d_in[24], (const float*)d_in[26],
      (const float*)d_in[27], (const float*)d_in[28],
      out_x, nullptr, NNODES);
}

// Round 3
// 1531.591 us; speedup vs baseline: 1.2383x; 1.2383x over previous
//
#include <hip/hip_runtime.h>

// InteractionNetwork — fused MFMA, transposed-product formulation.
// OUT^T = W^T * X^T per layer: weight frags persistent in VGPRs (A-operand),
// activation frags read row-major from swizzled LDS (B-operand). Epilogue
// writes LN'd rows to an fp32 LDS buffer, then a writer phase issues
// row-contiguous global stores (256B/row) and atomics (64B/row/instr) to
// avoid the R2 RMW amplification.

#define NNODES 50000
#define NEDGES 800000
#define NBLK 512

typedef __bf16 bf16x8 __attribute__((ext_vector_type(8)));
typedef float f32x4 __attribute__((ext_vector_type(4)));
#define MFMA(a, b, c) __builtin_amdgcn_mfma_f32_16x16x32_bf16(a, b, c, 0, 0, 0)

// LDS map (bytes)
#define OFF_A 0       // [64 rows][192 bf16] stride 384, XOR-swizzled; [0,256) reused as H1; [256,384) = residual seg
#define OFF_H0 24576  // [64 rows][128 bf16] stride 256, XOR-swizzled; reused as O [64][64] f32 after L1
#define OFF_O OFF_H0
#define OFF_SA 40960  // DMA strip: 16 chunks x (1024B data + 16B pad) = 16640
#define OFF_P 57600   // [64 rows][4 float2] partial (s,ss) = 2048
#define OFF_IX 59648  // [64] int dst indices = 256
#define SMEM 59904

__device__ __forceinline__ unsigned short f2bf(float f) {
  unsigned u = __builtin_bit_cast(unsigned, f);
  u = (u + 0x7fffu + ((u >> 16) & 1u)) >> 16;
  return (unsigned short)u;
}
__device__ __forceinline__ float bf2f(unsigned short h) {
  return __builtin_bit_cast(float, (unsigned)h << 16);
}
__device__ __forceinline__ unsigned long long pk4(f32x4 v) {
  union { unsigned short h[4]; unsigned long long u; } p;
  p.h[0] = f2bf(v[0]); p.h[1] = f2bf(v[1]); p.h[2] = f2bf(v[2]); p.h[3] = f2bf(v[3]);
  return p.u;
}
__device__ __forceinline__ void cvt8s(float4 f0, float4 f1, char* d) {
  union { unsigned short us[8]; int4 v; } u;
  u.us[0] = f2bf(f0.x); u.us[1] = f2bf(f0.y); u.us[2] = f2bf(f0.z); u.us[3] = f2bf(f0.w);
  u.us[4] = f2bf(f1.x); u.us[5] = f2bf(f1.y); u.us[6] = f2bf(f1.z); u.us[7] = f2bf(f1.w);
  *(int4*)d = u.v;
}

// EDGE: A = [x[dst] | x[src] | attr(DMA)], resid = attr, atomics into agg.
// NODE: A = [aggm | aggw | x(DMA)],       resid = x (seg2), no atomics.
//       (node W0 rows are pre-rotated by prep_w so concat order matches.)
template <bool EDGE>
__global__ __launch_bounds__(512, 4) void mlp_block(
    const float* __restrict__ g1, const float* __restrict__ g2,
    const float* __restrict__ g3, const int* __restrict__ srcI,
    const int* __restrict__ dstI, const unsigned short* __restrict__ Wt,
    const float* __restrict__ b0, const float* __restrict__ b1,
    const float* __restrict__ b2, const float* __restrict__ gam,
    const float* __restrict__ bet, float* __restrict__ outp,
    float* __restrict__ agg, int M) {
  __shared__ __align__(16) char sm[SMEM];
  const int tid = threadIdx.x, lane = tid & 63, wave = tid >> 6;
  const int lrow = lane & 15, cg = lane >> 4;
  const unsigned short* Wt0 = Wt;
  const unsigned short* Wt1 = Wt + 24576;
  const unsigned short* Wt2 = Wt + 40960;
  const int ntiles = (M + 63) >> 6;

  const int cg2 = wave & 3, rg = wave >> 2, ctb = cg2 * 2;

  // ---- persistent weight fragments (A-operand = W^T rows = out-cols) ----
  bf16x8 w0f[2][6], w1f[4], w2f[4];
#pragma unroll
  for (int i = 0; i < 2; ++i)
#pragma unroll
    for (int kk = 0; kk < 6; ++kk)
      w0f[i][kk] = *(const bf16x8*)(Wt0 + ((ctb + i) * 16 + lrow) * 192 + kk * 32 + cg * 8);
#pragma unroll
  for (int kk = 0; kk < 4; ++kk)
    w1f[kk] = *(const bf16x8*)(Wt1 + (wave * 16 + lrow) * 128 + kk * 32 + cg * 8);
#pragma unroll
  for (int kk = 0; kk < 4; ++kk)
    w2f[kk] = *(const bf16x8*)(Wt2 + (cg2 * 16 + lrow) * 128 + kk * 32 + cg * 8);

  // ---- persistent bias / LN params ----
  f32x4 bb0[2], bb1, bb2, gv, bv;
#pragma unroll
  for (int i = 0; i < 2; ++i) bb0[i] = *(const f32x4*)(b0 + (ctb + i) * 16 + cg * 4);
  bb1 = *(const f32x4*)(b1 + wave * 16 + cg * 4);
  bb2 = *(const f32x4*)(b2 + cg2 * 16 + cg * 4);
  gv = *(const f32x4*)(gam + cg2 * 16 + cg * 4);
  bv = *(const f32x4*)(bet + cg2 * 16 + cg * 4);

  // staging map: row = (tid>>5)*4 + ((tid&31)>>3), float-octet oct = tid&7
  const int srow = (tid >> 5) * 4 + ((tid & 31) >> 3), oct = tid & 7;

  int t = blockIdx.x;
  if (t >= ntiles) return;

  // ---- prologue: prefetch tile t ----
  float4 ga0, ga1, gb0, gb1;
  int dcur = 0;
  {
    int row = t * 64 + srow;
    int r1, r2;
    if (EDGE) { dcur = dstI[row]; r1 = dcur; r2 = srcI[row]; }
    else { int rr = min(row, M - 1); r1 = rr; r2 = rr; }
    const float* p1 = g1 + (size_t)r1 * 64 + oct * 8;
    const float* p2 = g2 + (size_t)r2 * 64 + oct * 8;
    ga0 = *(const float4*)p1; ga1 = *(const float4*)(p1 + 4);
    gb0 = *(const float4*)p2; gb1 = *(const float4*)(p2 + 4);
#pragma unroll
    for (int i = 0; i < 2; ++i) {
      int chunk = wave * 2 + i;
      const float* gsrc;
      if (EDGE) gsrc = g3 + (size_t)t * 4096 + chunk * 256 + lane * 4;
      else { int gr = min(t * 64 + chunk * 4 + (lane >> 4), M - 1); gsrc = g3 + (size_t)gr * 64 + (lane & 15) * 4; }
      __builtin_amdgcn_global_load_lds((const __attribute__((address_space(1))) unsigned int*)gsrc,
          (__attribute__((address_space(3))) unsigned int*)(sm + OFF_SA + chunk * 1040), 16, 0, 0);
    }
  }

  for (; t < ntiles; t += NBLK) {
    const int tn = t + NBLK;
    const bool more = tn < ntiles;
    __syncthreads();  // (a) strips+A+O free; DMA(t) drained
    // ---------------- W: regs + strip -> bf16 A tile ----------------
    {
      char* a0 = sm + OFF_A + srow * 384;
      const int swz = (srow & 7) << 4;
      cvt8s(ga0, ga1, a0 + ((oct * 16) ^ swz));
      cvt8s(gb0, gb1, a0 + ((128 + oct * 16) ^ swz));
      const char* sa = sm + OFF_SA + (srow >> 2) * 1040 + (srow & 3) * 256 + oct * 32;
      float4 c0 = *(const float4*)sa, c1 = *(const float4*)(sa + 16);
      cvt8s(c0, c1, a0 + ((256 + oct * 16) ^ swz));
      if (EDGE && (tid & 7) == 0) ((int*)(sm + OFF_IX))[srow] = dcur;
    }
    int dn = 0, sn = 0;
    if (EDGE && more) { int row = tn * 64 + srow; dn = dstI[row]; sn = srcI[row]; }
    __syncthreads();  // (b) A ready
    // ---------------- P: issue prefetch for tn ----------------
    if (more) {
      const float *p1, *p2;
      if (EDGE) {
        p1 = g1 + (size_t)dn * 64 + oct * 8;
        p2 = g2 + (size_t)sn * 64 + oct * 8;
        dcur = dn;
      } else {
        int rr = min(tn * 64 + srow, M - 1);
        p1 = g1 + (size_t)rr * 64 + oct * 8;
        p2 = g2 + (size_t)rr * 64 + oct * 8;
      }
      ga0 = *(const float4*)p1; ga1 = *(const float4*)(p1 + 4);
      gb0 = *(const float4*)p2; gb1 = *(const float4*)(p2 + 4);
#pragma unroll
      for (int i = 0; i < 2; ++i) {
        int chunk = wave * 2 + i;
        const float* gsrc;
        if (EDGE) gsrc = g3 + (size_t)tn * 4096 + chunk * 256 + lane * 4;
        else { int gr = min(tn * 64 + chunk * 4 + (lane >> 4), M - 1); gsrc = g3 + (size_t)gr * 64 + (lane & 15) * 4; }
        __builtin_amdgcn_global_load_lds((const __attribute__((address_space(1))) unsigned int*)gsrc,
            (__attribute__((address_space(3))) unsigned int*)(sm + OFF_SA + chunk * 1040), 16, 0, 0);
      }
    }
    // ---------------- L0: A[192] -> H0[128], relu ----------------
#pragma unroll
    for (int j = 0; j < 2; ++j) {
      const int rt = rg * 2 + j, row = rt * 16 + lrow, swz = (row & 7) << 4;
      const char* ab = sm + OFF_A + row * 384;
      f32x4 acc0 = {0.f, 0.f, 0.f, 0.f}, acc1 = {0.f, 0.f, 0.f, 0.f};
#pragma unroll
      for (int kk = 0; kk < 6; ++kk) {
        bf16x8 bf = *(const bf16x8*)(ab + ((kk * 64 + cg * 16) ^ swz));
        acc0 = MFMA(w0f[0][kk], bf, acc0);
        acc1 = MFMA(w0f[1][kk], bf, acc1);
      }
#pragma unroll
      for (int i = 0; i < 2; ++i) {
        f32x4 acc = i ? acc1 : acc0;
        f32x4 h;
#pragma unroll
        for (int q = 0; q < 4; ++q) h[q] = fmaxf(acc[q] + bb0[i][q], 0.f);
        *(unsigned long long*)(sm + OFF_H0 + row * 256 + (((ctb + i) * 32 + cg * 8) ^ swz)) = pk4(h);
      }
    }
    __syncthreads();  // (c) H0 ready
    // ---------------- L1: H0 -> H1 (A[0,256) overlay), relu ----------------
#pragma unroll
    for (int rt = 0; rt < 4; ++rt) {
      const int row = rt * 16 + lrow, swz = (row & 7) << 4;
      const char* hb = sm + OFF_H0 + row * 256;
      f32x4 acc = {0.f, 0.f, 0.f, 0.f};
#pragma unroll
      for (int kk = 0; kk < 4; ++kk)
        acc = MFMA(w1f[kk], *(const bf16x8*)(hb + ((kk * 64 + cg * 16) ^ swz)), acc);
      f32x4 h;
#pragma unroll
      for (int q = 0; q < 4; ++q) h[q] = fmaxf(acc[q] + bb1[q], 0.f);
      *(unsigned long long*)(sm + OFF_A + row * 384 + ((wave * 32 + cg * 8) ^ swz)) = pk4(h);
    }
    __syncthreads();  // (d) H1 ready (H0/O region now free)
    // ---------------- L2p: H1 -> acc + bias, LN partials ----------------
    f32x4 accE[2];
#pragma unroll
    for (int j = 0; j < 2; ++j) {
      const int rt = rg * 2 + j, row = rt * 16 + lrow, swz = (row & 7) << 4;
      const char* hb = sm + OFF_A + row * 384;
      f32x4 acc = {0.f, 0.f, 0.f, 0.f};
#pragma unroll
      for (int kk = 0; kk < 4; ++kk)
        acc = MFMA(w2f[kk], *(const bf16x8*)(hb + ((kk * 64 + cg * 16) ^ swz)), acc);
#pragma unroll
      for (int q = 0; q < 4; ++q) acc[q] += bb2[q];
      float s = acc[0] + acc[1] + acc[2] + acc[3];
      float ss = acc[0] * acc[0] + acc[1] * acc[1] + acc[2] * acc[2] + acc[3] * acc[3];
      s += __shfl_xor(s, 16, 64); s += __shfl_xor(s, 32, 64);
      ss += __shfl_xor(ss, 16, 64); ss += __shfl_xor(ss, 32, 64);
      if (cg == 0) *(float2*)(sm + OFF_P + row * 32 + cg2 * 8) = make_float2(s, ss);
      accE[j] = acc;
    }
    __syncthreads();  // (e) partials ready
    // ---------------- E2: LN + residual -> O (fp32, swizzled) ----------------
#pragma unroll
    for (int j = 0; j < 2; ++j) {
      const int rt = rg * 2 + j, row = rt * 16 + lrow;
      float4 p0 = *(const float4*)(sm + OFF_P + row * 32);
      float4 p1 = *(const float4*)(sm + OFF_P + row * 32 + 16);
      float s = p0.x + p0.z + p1.x + p1.z, ss = p0.y + p0.w + p1.y + p1.w;
      float mean = s * (1.f / 64.f);
      float var = fmaxf(ss * (1.f / 64.f) - mean * mean, 0.f);
      float inv = rsqrtf(var + 1e-5f);
      const int swz = (row & 7) << 4;
      unsigned long long rv =
          *(const unsigned long long*)(sm + OFF_A + row * 384 + ((256 + cg2 * 32 + cg * 8) ^ swz));
      f32x4 a = accE[j];
      f32x4 o;
      o[0] = (a[0] - mean) * inv * gv[0] + bv[0] + bf2f((unsigned short)rv);
      o[1] = (a[1] - mean) * inv * gv[1] + bv[1] + bf2f((unsigned short)(rv >> 16));
      o[2] = (a[2] - mean) * inv * gv[2] + bv[2] + bf2f((unsigned short)(rv >> 32));
      o[3] = (a[3] - mean) * inv * gv[3] + bv[3] + bf2f((unsigned short)(rv >> 48));
      *(f32x4*)(sm + OFF_O + row * 256 + ((cg2 * 64 + cg * 16) ^ ((row & 15) << 4))) = o;
    }
    __syncthreads();  // (f) O ready
    // ---------------- WR: coalesced stores + atomics ----------------
#pragma unroll
    for (int j = 0; j < 2; ++j) {
      const int row = wave * 8 + j * 4 + cg, gr = t * 64 + row;
      const int cq = lrow;
      const bool ok = EDGE || gr < M;
      f32x4 v = *(const f32x4*)(sm + OFF_O + row * 256 + ((cq * 16) ^ ((row & 15) << 4)));
      if (ok) *(f32x4*)(outp + (size_t)gr * 64 + cq * 4) = v;
      if (EDGE) {
        const int d = ((const int*)(sm + OFF_IX))[row];
        float* ap = agg + (size_t)d * 64;
#pragma unroll
        for (int k = 0; k < 4; ++k) {
          float sv = *(const float*)(sm + OFF_O + row * 256 + (((cq + k * 16) * 4) ^ ((row & 15) << 4)));
          atomicAdd(ap + cq + k * 16, sv);
        }
      }
    }
  }
}

// ---- prep: transpose+cast weights to bf16 [out][in]; rotate upd-W0 rows by 64
//      (node concat stored as [aggm|aggw|x] so x lands in the DMA segment) ----
struct PrepArgs { const float* w[9]; unsigned short* wt[3]; };

__global__ void prep_w(PrepArgs pa) {
  int i = blockIdx.x * 256 + threadIdx.x;
  if (i >= 3 * 49152) return;
  int mlp = i / 49152;
  int rem = i - mlp * 49152;
  int mat, off, K, N;
  if (rem < 24576)      { mat = 0; off = 0;     K = 192; N = 128; }
  else if (rem < 40960) { mat = 1; off = 24576; K = 128; N = 128; }
  else                  { mat = 2; off = 40960; K = 128; N = 64;  }
  int local = rem - off;
  int n = local / K, k = local - n * K;
  if (mlp == 2 && mat == 0) k = (k + 64) % 192;  // concat rotation for node MLP
  pa.wt[mlp][rem] = f2bf(pa.w[mlp * 3 + mat][k * N + n]);
}

__global__ void zero_f4(float4* p, int n) {
  int i = blockIdx.x * blockDim.x + threadIdx.x;
  if (i < n) p[i] = make_float4(0.f, 0.f, 0.f, 0.f);
}

extern "C" void kernel_launch(void* const* d_in, const int* in_sizes, int n_in,
                              void* d_out, int out_size, void* d_ws, size_t ws_size,
                              hipStream_t stream) {
  const float* x      = (const float*)d_in[0];
  const int*   meIdx  = (const int*)d_in[1];
  const float* meAttr = (const float*)d_in[2];
  const int*   weIdx  = (const int*)d_in[3];
  const float* weAttr = (const float*)d_in[4];

  float* out_x  = (float*)d_out;
  float* out_em = out_x + (size_t)NNODES * 64;
  float* out_ew = out_em + (size_t)NEDGES * 64;

  char* ws = (char*)d_ws;
  unsigned short* WtM = (unsigned short*)ws;
  unsigned short* WtW = (unsigned short*)(ws + 98304);
  unsigned short* WtU = (unsigned short*)(ws + 196608);
  float* aggm = (float*)(ws + 294912);
  float* aggw = aggm + (size_t)NNODES * 64;

  zero_f4<<<dim3(6250), dim3(256), 0, stream>>>((float4*)aggm, 1600000);

  PrepArgs pa;
  for (int m = 0; m < 3; ++m)
    for (int l = 0; l < 3; ++l)
      pa.w[m * 3 + l] = (const float*)d_in[5 + m * 8 + l * 2];
  pa.wt[0] = WtM; pa.wt[1] = WtW; pa.wt[2] = WtU;
  prep_w<<<dim3(576), dim3(256), 0, stream>>>(pa);

  // mesh edges: src = row0, dst = row1; x_i = x[dst], x_j = x[src]
  mlp_block<true><<<dim3(NBLK), dim3(512), 0, stream>>>(
      x, x, meAttr, meIdx, meIdx + NEDGES, WtM,
      (const float*)d_in[6], (const float*)d_in[8], (const float*)d_in[10],
      (const float*)d_in[11], (const float*)d_in[12],
      out_em, aggm, NEDGES);
  // world edges
  mlp_block<true><<<dim3(NBLK), dim3(512), 0, stream>>>(
      x, x, weAttr, weIdx, weIdx + NEDGES, WtW,
      (const float*)d_in[14], (const float*)d_in[16], (const float*)d_in[18],
      (const float*)d_in[19], (const float*)d_in[20],
      out_ew, aggw, NEDGES);
  // node update: A = [aggm | aggw | x], residual = x
  mlp_block<false><<<dim3(NBLK), dim3(512), 0, stream>>>(
      aggm, aggw, x, nullptr, nullptr, WtU,
      (const float*)d_in[22], (const float*)d_in[24], (const float*)d_in[26],
      (const float*)d_in[27], (const float*)d_in[28],
      out_x, nullptr, NNODES);
}

// Round 4
// 987.260 us; speedup vs baseline: 1.9210x; 1.5514x over previous
//
#include <hip/hip_runtime.h>

// InteractionNetwork — fused MFMA, transposed-product formulation.
// OUT^T = W^T * X^T per layer: weight frags persistent in VGPRs (A-operand),
// DEDUPED across waves (L0: one coltile per wave) so the whole thread state
// fits in the 128-VGPR cap of __launch_bounds__(512,4) with no scratch spill.
// Activation frags read row-major from swizzled LDS (B-operand). Epilogue
// writes LN'd rows to an fp32 LDS buffer, then a writer phase issues
// row-contiguous global stores (256B/row) and atomics (64B/row/instr).

#define NNODES 50000
#define NEDGES 800000
#define NBLK 512

typedef __bf16 bf16x8 __attribute__((ext_vector_type(8)));
typedef float f32x4 __attribute__((ext_vector_type(4)));
#define MFMA(a, b, c) __builtin_amdgcn_mfma_f32_16x16x32_bf16(a, b, c, 0, 0, 0)

// LDS map (bytes)
#define OFF_A 0       // [64 rows][192 bf16] stride 384, XOR-swizzled; [0,256) reused as H1; [256,384) = residual seg
#define OFF_H0 24576  // [64 rows][128 bf16] stride 256, XOR-swizzled; reused as O [64][64] f32 after L1
#define OFF_O OFF_H0
#define OFF_SA 40960  // DMA strip: 16 chunks x (1024B data + 16B pad) = 16640
#define OFF_P 57600   // [64 rows][4 float2] partial (s,ss) = 2048
#define OFF_IX 59648  // [64] int dst indices = 256
#define SMEM 59904

__device__ __forceinline__ unsigned short f2bf(float f) {
  unsigned u = __builtin_bit_cast(unsigned, f);
  u = (u + 0x7fffu + ((u >> 16) & 1u)) >> 16;
  return (unsigned short)u;
}
__device__ __forceinline__ float bf2f(unsigned short h) {
  return __builtin_bit_cast(float, (unsigned)h << 16);
}
__device__ __forceinline__ unsigned long long pk4(f32x4 v) {
  union { unsigned short h[4]; unsigned long long u; } p;
  p.h[0] = f2bf(v[0]); p.h[1] = f2bf(v[1]); p.h[2] = f2bf(v[2]); p.h[3] = f2bf(v[3]);
  return p.u;
}
__device__ __forceinline__ void cvt8s(float4 f0, float4 f1, char* d) {
  union { unsigned short us[8]; int4 v; } u;
  u.us[0] = f2bf(f0.x); u.us[1] = f2bf(f0.y); u.us[2] = f2bf(f0.z); u.us[3] = f2bf(f0.w);
  u.us[4] = f2bf(f1.x); u.us[5] = f2bf(f1.y); u.us[6] = f2bf(f1.z); u.us[7] = f2bf(f1.w);
  *(int4*)d = u.v;
}

// EDGE: A = [x[dst] | x[src] | attr(DMA)], resid = attr, atomics into agg.
// NODE: A = [aggm | aggw | x(DMA)],       resid = x (seg2), no atomics.
//       (node W0 rows are pre-rotated by prep_w so concat order matches.)
template <bool EDGE>
__global__ __launch_bounds__(512, 4) void mlp_block(
    const float* __restrict__ g1, const float* __restrict__ g2,
    const float* __restrict__ g3, const int* __restrict__ srcI,
    const int* __restrict__ dstI, const unsigned short* __restrict__ Wt,
    const float* __restrict__ b0, const float* __restrict__ b1,
    const float* __restrict__ b2, const float* __restrict__ gam,
    const float* __restrict__ bet, float* __restrict__ outp,
    float* __restrict__ agg, int M) {
  __shared__ __align__(16) char sm[SMEM];
  const int tid = threadIdx.x, lane = tid & 63, wave = tid >> 6;
  const int lrow = lane & 15, cg = lane >> 4;
  const unsigned short* Wt0 = Wt;
  const unsigned short* Wt1 = Wt + 24576;
  const unsigned short* Wt2 = Wt + 40960;
  const int ntiles = (M + 63) >> 6;

  const int cg2 = wave & 3, rg = wave >> 2;

  // ---- persistent weight fragments, deduped (A-operand = W^T rows = out-cols) ----
  // L0: wave owns coltile `wave` (24 VGPR); L1: coltile `wave` (16); L2: coltile cg2 (16).
  bf16x8 w0f[6], w1f[4], w2f[4];
#pragma unroll
  for (int kk = 0; kk < 6; ++kk)
    w0f[kk] = *(const bf16x8*)(Wt0 + (wave * 16 + lrow) * 192 + kk * 32 + cg * 8);
#pragma unroll
  for (int kk = 0; kk < 4; ++kk)
    w1f[kk] = *(const bf16x8*)(Wt1 + (wave * 16 + lrow) * 128 + kk * 32 + cg * 8);
#pragma unroll
  for (int kk = 0; kk < 4; ++kk)
    w2f[kk] = *(const bf16x8*)(Wt2 + (cg2 * 16 + lrow) * 128 + kk * 32 + cg * 8);

  // ---- persistent bias / LN params ----
  f32x4 bb0, bb1, bb2, gv, bv;
  bb0 = *(const f32x4*)(b0 + wave * 16 + cg * 4);
  bb1 = *(const f32x4*)(b1 + wave * 16 + cg * 4);
  bb2 = *(const f32x4*)(b2 + cg2 * 16 + cg * 4);
  gv = *(const f32x4*)(gam + cg2 * 16 + cg * 4);
  bv = *(const f32x4*)(bet + cg2 * 16 + cg * 4);

  // staging map: row = (tid>>5)*4 + ((tid&31)>>3), float-octet oct = tid&7
  const int srow = (tid >> 5) * 4 + ((tid & 31) >> 3), oct = tid & 7;

  int t = blockIdx.x;
  if (t >= ntiles) return;

  // ---- prologue: prefetch tile t ----
  float4 ga0, ga1, gb0, gb1;
  int dcur = 0;
  {
    int row = t * 64 + srow;
    int r1, r2;
    if (EDGE) { dcur = dstI[row]; r1 = dcur; r2 = srcI[row]; }
    else { int rr = min(row, M - 1); r1 = rr; r2 = rr; }
    const float* p1 = g1 + (size_t)r1 * 64 + oct * 8;
    const float* p2 = g2 + (size_t)r2 * 64 + oct * 8;
    ga0 = *(const float4*)p1; ga1 = *(const float4*)(p1 + 4);
    gb0 = *(const float4*)p2; gb1 = *(const float4*)(p2 + 4);
#pragma unroll
    for (int i = 0; i < 2; ++i) {
      int chunk = wave * 2 + i;
      const float* gsrc;
      if (EDGE) gsrc = g3 + (size_t)t * 4096 + chunk * 256 + lane * 4;
      else { int gr = min(t * 64 + chunk * 4 + (lane >> 4), M - 1); gsrc = g3 + (size_t)gr * 64 + (lane & 15) * 4; }
      __builtin_amdgcn_global_load_lds((const __attribute__((address_space(1))) unsigned int*)gsrc,
          (__attribute__((address_space(3))) unsigned int*)(sm + OFF_SA + chunk * 1040), 16, 0, 0);
    }
  }

  for (; t < ntiles; t += NBLK) {
    const int tn = t + NBLK;
    const bool more = tn < ntiles;
    __syncthreads();  // (a) strips+A+O free; DMA(t) drained
    // ---------------- W: regs + strip -> bf16 A tile ----------------
    {
      char* a0 = sm + OFF_A + srow * 384;
      const int swz = (srow & 7) << 4;
      cvt8s(ga0, ga1, a0 + ((oct * 16) ^ swz));
      cvt8s(gb0, gb1, a0 + ((128 + oct * 16) ^ swz));
      const char* sa = sm + OFF_SA + (srow >> 2) * 1040 + (srow & 3) * 256 + oct * 32;
      float4 c0 = *(const float4*)sa, c1 = *(const float4*)(sa + 16);
      cvt8s(c0, c1, a0 + ((256 + oct * 16) ^ swz));
      if (EDGE && (tid & 7) == 0) ((int*)(sm + OFF_IX))[srow] = dcur;
    }
    int dn = 0, sn = 0;
    if (EDGE && more) { int row = tn * 64 + srow; dn = dstI[row]; sn = srcI[row]; }
    __syncthreads();  // (b) A ready
    // ---------------- P: issue prefetch for tn ----------------
    if (more) {
      const float *p1, *p2;
      if (EDGE) {
        p1 = g1 + (size_t)dn * 64 + oct * 8;
        p2 = g2 + (size_t)sn * 64 + oct * 8;
        dcur = dn;
      } else {
        int rr = min(tn * 64 + srow, M - 1);
        p1 = g1 + (size_t)rr * 64 + oct * 8;
        p2 = g2 + (size_t)rr * 64 + oct * 8;
      }
      ga0 = *(const float4*)p1; ga1 = *(const float4*)(p1 + 4);
      gb0 = *(const float4*)p2; gb1 = *(const float4*)(p2 + 4);
#pragma unroll
      for (int i = 0; i < 2; ++i) {
        int chunk = wave * 2 + i;
        const float* gsrc;
        if (EDGE) gsrc = g3 + (size_t)tn * 4096 + chunk * 256 + lane * 4;
        else { int gr = min(tn * 64 + chunk * 4 + (lane >> 4), M - 1); gsrc = g3 + (size_t)gr * 64 + (lane & 15) * 4; }
        __builtin_amdgcn_global_load_lds((const __attribute__((address_space(1))) unsigned int*)gsrc,
            (__attribute__((address_space(3))) unsigned int*)(sm + OFF_SA + chunk * 1040), 16, 0, 0);
      }
    }
    // ---------------- L0: A[192] -> H0[128], relu (wave = its coltile, all 4 row-tiles) ----------------
#pragma unroll
    for (int rt = 0; rt < 4; ++rt) {
      const int row = rt * 16 + lrow, swz = (row & 7) << 4;
      const char* ab = sm + OFF_A + row * 384;
      f32x4 acc = {0.f, 0.f, 0.f, 0.f};
#pragma unroll
      for (int kk = 0; kk < 6; ++kk)
        acc = MFMA(w0f[kk], *(const bf16x8*)(ab + ((kk * 64 + cg * 16) ^ swz)), acc);
      f32x4 h;
#pragma unroll
      for (int q = 0; q < 4; ++q) h[q] = fmaxf(acc[q] + bb0[q], 0.f);
      *(unsigned long long*)(sm + OFF_H0 + row * 256 + ((wave * 32 + cg * 8) ^ swz)) = pk4(h);
    }
    __syncthreads();  // (c) H0 ready
    // ---------------- L1: H0 -> H1 (A[0,256) overlay), relu ----------------
#pragma unroll
    for (int rt = 0; rt < 4; ++rt) {
      const int row = rt * 16 + lrow, swz = (row & 7) << 4;
      const char* hb = sm + OFF_H0 + row * 256;
      f32x4 acc = {0.f, 0.f, 0.f, 0.f};
#pragma unroll
      for (int kk = 0; kk < 4; ++kk)
        acc = MFMA(w1f[kk], *(const bf16x8*)(hb + ((kk * 64 + cg * 16) ^ swz)), acc);
      f32x4 h;
#pragma unroll
      for (int q = 0; q < 4; ++q) h[q] = fmaxf(acc[q] + bb1[q], 0.f);
      *(unsigned long long*)(sm + OFF_A + row * 384 + ((wave * 32 + cg * 8) ^ swz)) = pk4(h);
    }
    __syncthreads();  // (d) H1 ready (H0/O region now free)
    // ---------------- L2p: H1 -> acc + bias, LN partials ----------------
    f32x4 accE[2];
#pragma unroll
    for (int j = 0; j < 2; ++j) {
      const int rt = rg * 2 + j, row = rt * 16 + lrow, swz = (row & 7) << 4;
      const char* hb = sm + OFF_A + row * 384;
      f32x4 acc = {0.f, 0.f, 0.f, 0.f};
#pragma unroll
      for (int kk = 0; kk < 4; ++kk)
        acc = MFMA(w2f[kk], *(const bf16x8*)(hb + ((kk * 64 + cg * 16) ^ swz)), acc);
#pragma unroll
      for (int q = 0; q < 4; ++q) acc[q] += bb2[q];
      float s = acc[0] + acc[1] + acc[2] + acc[3];
      float ss = acc[0] * acc[0] + acc[1] * acc[1] + acc[2] * acc[2] + acc[3] * acc[3];
      s += __shfl_xor(s, 16, 64); s += __shfl_xor(s, 32, 64);
      ss += __shfl_xor(ss, 16, 64); ss += __shfl_xor(ss, 32, 64);
      if (cg == 0) *(float2*)(sm + OFF_P + row * 32 + cg2 * 8) = make_float2(s, ss);
      accE[j] = acc;
    }
    __syncthreads();  // (e) partials ready
    // ---------------- E2: LN + residual -> O (fp32, swizzled) ----------------
#pragma unroll
    for (int j = 0; j < 2; ++j) {
      const int rt = rg * 2 + j, row = rt * 16 + lrow;
      float4 p0 = *(const float4*)(sm + OFF_P + row * 32);
      float4 p1 = *(const float4*)(sm + OFF_P + row * 32 + 16);
      float s = p0.x + p0.z + p1.x + p1.z, ss = p0.y + p0.w + p1.y + p1.w;
      float mean = s * (1.f / 64.f);
      float var = fmaxf(ss * (1.f / 64.f) - mean * mean, 0.f);
      float inv = rsqrtf(var + 1e-5f);
      const int swz = (row & 7) << 4;
      unsigned long long rv =
          *(const unsigned long long*)(sm + OFF_A + row * 384 + ((256 + cg2 * 32 + cg * 8) ^ swz));
      f32x4 a = accE[j];
      f32x4 o;
      o[0] = (a[0] - mean) * inv * gv[0] + bv[0] + bf2f((unsigned short)rv);
      o[1] = (a[1] - mean) * inv * gv[1] + bv[1] + bf2f((unsigned short)(rv >> 16));
      o[2] = (a[2] - mean) * inv * gv[2] + bv[2] + bf2f((unsigned short)(rv >> 32));
      o[3] = (a[3] - mean) * inv * gv[3] + bv[3] + bf2f((unsigned short)(rv >> 48));
      *(f32x4*)(sm + OFF_O + row * 256 + ((cg2 * 64 + cg * 16) ^ ((row & 15) << 4))) = o;
    }
    __syncthreads();  // (f) O ready
    // ---------------- WR: coalesced stores + atomics ----------------
#pragma unroll
    for (int j = 0; j < 2; ++j) {
      const int row = wave * 8 + j * 4 + cg, gr = t * 64 + row;
      const int cq = lrow;
      const bool ok = EDGE || gr < M;
      f32x4 v = *(const f32x4*)(sm + OFF_O + row * 256 + ((cq * 16) ^ ((row & 15) << 4)));
      if (ok) *(f32x4*)(outp + (size_t)gr * 64 + cq * 4) = v;
      if (EDGE) {
        const int d = ((const int*)(sm + OFF_IX))[row];
        float* ap = agg + (size_t)d * 64;
#pragma unroll
        for (int k = 0; k < 4; ++k) {
          float sv = *(const float*)(sm + OFF_O + row * 256 + (((cq + k * 16) * 4) ^ ((row & 15) << 4)));
          atomicAdd(ap + cq + k * 16, sv);
        }
      }
    }
  }
}

// ---- prep: transpose+cast weights to bf16 [out][in]; rotate upd-W0 rows by 64
//      (node concat stored as [aggm|aggw|x] so x lands in the DMA segment) ----
struct PrepArgs { const float* w[9]; unsigned short* wt[3]; };

__global__ void prep_w(PrepArgs pa) {
  int i = blockIdx.x * 256 + threadIdx.x;
  if (i >= 3 * 49152) return;
  int mlp = i / 49152;
  int rem = i - mlp * 49152;
  int mat, off, K, N;
  if (rem < 24576)      { mat = 0; off = 0;     K = 192; N = 128; }
  else if (rem < 40960) { mat = 1; off = 24576; K = 128; N = 128; }
  else                  { mat = 2; off = 40960; K = 128; N = 64;  }
  int local = rem - off;
  int n = local / K, k = local - n * K;
  if (mlp == 2 && mat == 0) k = (k + 64) % 192;  // concat rotation for node MLP
  pa.wt[mlp][rem] = f2bf(pa.w[mlp * 3 + mat][k * N + n]);
}

__global__ void zero_f4(float4* p, int n) {
  int i = blockIdx.x * blockDim.x + threadIdx.x;
  if (i < n) p[i] = make_float4(0.f, 0.f, 0.f, 0.f);
}

extern "C" void kernel_launch(void* const* d_in, const int* in_sizes, int n_in,
                              void* d_out, int out_size, void* d_ws, size_t ws_size,
                              hipStream_t stream) {
  const float* x      = (const float*)d_in[0];
  const int*   meIdx  = (const int*)d_in[1];
  const float* meAttr = (const float*)d_in[2];
  const int*   weIdx  = (const int*)d_in[3];
  const float* weAttr = (const float*)d_in[4];

  float* out_x  = (float*)d_out;
  float* out_em = out_x + (size_t)NNODES * 64;
  float* out_ew = out_em + (size_t)NEDGES * 64;

  char* ws = (char*)d_ws;
  unsigned short* WtM = (unsigned short*)ws;
  unsigned short* WtW = (unsigned short*)(ws + 98304);
  unsigned short* WtU = (unsigned short*)(ws + 196608);
  float* aggm = (float*)(ws + 294912);
  float* aggw = aggm + (size_t)NNODES * 64;

  zero_f4<<<dim3(6250), dim3(256), 0, stream>>>((float4*)aggm, 1600000);

  PrepArgs pa;
  for (int m = 0; m < 3; ++m)
    for (int l = 0; l < 3; ++l)
      pa.w[m * 3 + l] = (const float*)d_in[5 + m * 8 + l * 2];
  pa.wt[0] = WtM; pa.wt[1] = WtW; pa.wt[2] = WtU;
  prep_w<<<dim3(576), dim3(256), 0, stream>>>(pa);

  // mesh edges: src = row0, dst = row1; x_i = x[dst], x_j = x[src]
  mlp_block<true><<<dim3(NBLK), dim3(512), 0, stream>>>(
      x, x, meAttr, meIdx, meIdx + NEDGES, WtM,
      (const float*)d_in[6], (const float*)d_in[8], (const float*)d_in[10],
      (const float*)d_in[11], (const float*)d_in[12],
      out_em, aggm, NEDGES);
  // world edges
  mlp_block<true><<<dim3(NBLK), dim3(512), 0, stream>>>(
      x, x, weAttr, weIdx, weIdx + NEDGES, WtW,
      (const float*)d_in[14], (const float*)d_in[16], (const float*)d_in[18],
      (const float*)d_in[19], (const float*)d_in[20],
      out_ew, aggw, NEDGES);
  // node update: A = [aggm | aggw | x], residual = x
  mlp_block<false><<<dim3(NBLK), dim3(512), 0, stream>>>(
      aggm, aggw, x, nullptr, nullptr, WtU,
      (const float*)d_in[22], (const float*)d_in[24], (const float*)d_in[26],
      (const float*)d_in[27], (const float*)d_in[28],
      out_x, nullptr, NNODES);
}

// Round 5
// 890.218 us; speedup vs baseline: 2.1305x; 1.1090x over previous
//
#include <hip/hip_runtime.h>

// InteractionNetwork — fused MFMA, transposed-product formulation.
// OUT^T = W^T * X^T per layer: weight frags persistent in VGPRs/AGPRs
// (A-operand), deduped across waves. Bias/LN params live in LDS (not regs)
// to keep unified VGPR+AGPR demand under the 128-reg cap of
// __launch_bounds__(512,4) — R2-R4 showed scratch-spill traffic reaching
// HBM whenever demand exceeded the cap. Epilogue writes LN'd rows to an
// fp32 LDS buffer, then a writer phase issues row-contiguous global stores
// (256B/row) and atomics (64B/row/instr).

#define NNODES 50000
#define NEDGES 800000
#define NBLK 512

typedef __bf16 bf16x8 __attribute__((ext_vector_type(8)));
typedef float f32x4 __attribute__((ext_vector_type(4)));
#define MFMA(a, b, c) __builtin_amdgcn_mfma_f32_16x16x32_bf16(a, b, c, 0, 0, 0)

// LDS map (bytes)
#define OFF_A 0       // [64 rows][192 bf16] stride 384, XOR-swizzled; [0,256) reused as H1; [256,384) = residual seg
#define OFF_H0 24576  // [64 rows][128 bf16] stride 256, XOR-swizzled; reused as O [64][64] f32 after L1
#define OFF_O OFF_H0
#define OFF_SA 40960  // DMA strip: 16 chunks x (1024B data + 16B pad) = 16640
#define OFF_P 57600   // [64 rows][4 float2] partial (s,ss) = 2048
#define OFF_IX 59648  // [64] int dst indices = 256
#define OFF_PAR 59904 // param block: b0[128] b1[128] b2[64] gam[64] bet[64] = 448 f32
#define SMEM 61696

__device__ __forceinline__ unsigned short f2bf(float f) {
  unsigned u = __builtin_bit_cast(unsigned, f);
  u = (u + 0x7fffu + ((u >> 16) & 1u)) >> 16;
  return (unsigned short)u;
}
__device__ __forceinline__ float bf2f(unsigned short h) {
  return __builtin_bit_cast(float, (unsigned)h << 16);
}
__device__ __forceinline__ unsigned long long pk4(f32x4 v) {
  union { unsigned short h[4]; unsigned long long u; } p;
  p.h[0] = f2bf(v[0]); p.h[1] = f2bf(v[1]); p.h[2] = f2bf(v[2]); p.h[3] = f2bf(v[3]);
  return p.u;
}
__device__ __forceinline__ void cvt8s(float4 f0, float4 f1, char* d) {
  union { unsigned short us[8]; int4 v; } u;
  u.us[0] = f2bf(f0.x); u.us[1] = f2bf(f0.y); u.us[2] = f2bf(f0.z); u.us[3] = f2bf(f0.w);
  u.us[4] = f2bf(f1.x); u.us[5] = f2bf(f1.y); u.us[6] = f2bf(f1.z); u.us[7] = f2bf(f1.w);
  *(int4*)d = u.v;
}

// EDGE: A = [x[dst] | x[src] | attr(DMA)], resid = attr, atomics into agg.
// NODE: A = [aggm | aggw | x(DMA)],       resid = x (seg2), no atomics.
//       (node W0 rows are pre-rotated by prep_w so concat order matches.)
template <bool EDGE>
__global__ __launch_bounds__(512, 4) void mlp_block(
    const float* __restrict__ g1, const float* __restrict__ g2,
    const float* __restrict__ g3, const int* __restrict__ srcI,
    const int* __restrict__ dstI, const unsigned short* __restrict__ Wt,
    const float* __restrict__ b0, const float* __restrict__ b1,
    const float* __restrict__ b2, const float* __restrict__ gam,
    const float* __restrict__ bet, float* __restrict__ outp,
    float* __restrict__ agg, int M) {
  __shared__ __align__(16) char sm[SMEM];
  const int tid = threadIdx.x, lane = tid & 63, wave = tid >> 6;
  const int lrow = lane & 15, cg = lane >> 4;
  const unsigned short* Wt0 = Wt;
  const unsigned short* Wt1 = Wt + 24576;
  const unsigned short* Wt2 = Wt + 40960;
  const int ntiles = (M + 63) >> 6;

  const int cg2 = wave & 3, rg = wave >> 2;

  // ---- stage bias/LN params into LDS (regalloc reads them per phase) ----
  for (int i = tid; i < 448; i += 512) {
    float v;
    if (i < 128) v = b0[i];
    else if (i < 256) v = b1[i - 128];
    else if (i < 320) v = b2[i - 256];
    else if (i < 384) v = gam[i - 320];
    else v = bet[i - 384];
    ((float*)(sm + OFF_PAR))[i] = v;
  }
  const float* PAR = (const float*)(sm + OFF_PAR);

  // ---- persistent weight fragments, deduped (A-operand = W^T rows = out-cols) ----
  // L0: wave owns coltile `wave` (24 regs); L1: coltile `wave` (16); L2: coltile cg2 (16).
  bf16x8 w0f[6], w1f[4], w2f[4];
#pragma unroll
  for (int kk = 0; kk < 6; ++kk)
    w0f[kk] = *(const bf16x8*)(Wt0 + (wave * 16 + lrow) * 192 + kk * 32 + cg * 8);
#pragma unroll
  for (int kk = 0; kk < 4; ++kk)
    w1f[kk] = *(const bf16x8*)(Wt1 + (wave * 16 + lrow) * 128 + kk * 32 + cg * 8);
#pragma unroll
  for (int kk = 0; kk < 4; ++kk)
    w2f[kk] = *(const bf16x8*)(Wt2 + (cg2 * 16 + lrow) * 128 + kk * 32 + cg * 8);

  // staging map: row = (tid>>5)*4 + ((tid&31)>>3), float-octet oct = tid&7
  const int srow = (tid >> 5) * 4 + ((tid & 31) >> 3), oct = tid & 7;

  int t = blockIdx.x;
  if (t >= ntiles) return;

  // ---- prologue: prefetch tile t ----
  float4 ga0, ga1, gb0, gb1;
  int dcur = 0;
  {
    int row = t * 64 + srow;
    int r1, r2;
    if (EDGE) { dcur = dstI[row]; r1 = dcur; r2 = srcI[row]; }
    else { int rr = min(row, M - 1); r1 = rr; r2 = rr; }
    const float* p1 = g1 + (size_t)r1 * 64 + oct * 8;
    const float* p2 = g2 + (size_t)r2 * 64 + oct * 8;
    ga0 = *(const float4*)p1; ga1 = *(const float4*)(p1 + 4);
    gb0 = *(const float4*)p2; gb1 = *(const float4*)(p2 + 4);
#pragma unroll
    for (int i = 0; i < 2; ++i) {
      int chunk = wave * 2 + i;
      const float* gsrc;
      if (EDGE) gsrc = g3 + (size_t)t * 4096 + chunk * 256 + lane * 4;
      else { int gr = min(t * 64 + chunk * 4 + (lane >> 4), M - 1); gsrc = g3 + (size_t)gr * 64 + (lane & 15) * 4; }
      __builtin_amdgcn_global_load_lds((const __attribute__((address_space(1))) unsigned int*)gsrc,
          (__attribute__((address_space(3))) unsigned int*)(sm + OFF_SA + chunk * 1040), 16, 0, 0);
    }
  }

  for (; t < ntiles; t += NBLK) {
    const int tn = t + NBLK;
    const bool more = tn < ntiles;
    __syncthreads();  // (a) strips+A+O free; DMA(t) drained; params ready (1st iter)
    // ---------------- W: regs + strip -> bf16 A tile ----------------
    {
      char* a0 = sm + OFF_A + srow * 384;
      const int swz = (srow & 7) << 4;
      cvt8s(ga0, ga1, a0 + ((oct * 16) ^ swz));
      cvt8s(gb0, gb1, a0 + ((128 + oct * 16) ^ swz));
      const char* sa = sm + OFF_SA + (srow >> 2) * 1040 + (srow & 3) * 256 + oct * 32;
      float4 c0 = *(const float4*)sa, c1 = *(const float4*)(sa + 16);
      cvt8s(c0, c1, a0 + ((256 + oct * 16) ^ swz));
      if (EDGE && (tid & 7) == 0) ((int*)(sm + OFF_IX))[srow] = dcur;
    }
    int dn = 0, sn = 0;
    if (EDGE && more) { int row = tn * 64 + srow; dn = dstI[row]; sn = srcI[row]; }
    __syncthreads();  // (b) A ready
    // ---------------- P: issue prefetch for tn ----------------
    if (more) {
      const float *p1, *p2;
      if (EDGE) {
        p1 = g1 + (size_t)dn * 64 + oct * 8;
        p2 = g2 + (size_t)sn * 64 + oct * 8;
        dcur = dn;
      } else {
        int rr = min(tn * 64 + srow, M - 1);
        p1 = g1 + (size_t)rr * 64 + oct * 8;
        p2 = g2 + (size_t)rr * 64 + oct * 8;
      }
      ga0 = *(const float4*)p1; ga1 = *(const float4*)(p1 + 4);
      gb0 = *(const float4*)p2; gb1 = *(const float4*)(p2 + 4);
#pragma unroll
      for (int i = 0; i < 2; ++i) {
        int chunk = wave * 2 + i;
        const float* gsrc;
        if (EDGE) gsrc = g3 + (size_t)tn * 4096 + chunk * 256 + lane * 4;
        else { int gr = min(tn * 64 + chunk * 4 + (lane >> 4), M - 1); gsrc = g3 + (size_t)gr * 64 + (lane & 15) * 4; }
        __builtin_amdgcn_global_load_lds((const __attribute__((address_space(1))) unsigned int*)gsrc,
            (__attribute__((address_space(3))) unsigned int*)(sm + OFF_SA + chunk * 1040), 16, 0, 0);
      }
    }
    // ---------------- L0: A[192] -> H0[128], relu (wave = its coltile, all 4 row-tiles) ----------------
    {
      const f32x4 bb0 = *(const f32x4*)(PAR + wave * 16 + cg * 4);
#pragma unroll
      for (int rt = 0; rt < 4; ++rt) {
        const int row = rt * 16 + lrow, swz = (row & 7) << 4;
        const char* ab = sm + OFF_A + row * 384;
        f32x4 acc = {0.f, 0.f, 0.f, 0.f};
#pragma unroll
        for (int kk = 0; kk < 6; ++kk)
          acc = MFMA(w0f[kk], *(const bf16x8*)(ab + ((kk * 64 + cg * 16) ^ swz)), acc);
        f32x4 h;
#pragma unroll
        for (int q = 0; q < 4; ++q) h[q] = fmaxf(acc[q] + bb0[q], 0.f);
        *(unsigned long long*)(sm + OFF_H0 + row * 256 + ((wave * 32 + cg * 8) ^ swz)) = pk4(h);
      }
    }
    __syncthreads();  // (c) H0 ready
    // ---------------- L1: H0 -> H1 (A[0,256) overlay), relu ----------------
    {
      const f32x4 bb1 = *(const f32x4*)(PAR + 128 + wave * 16 + cg * 4);
#pragma unroll
      for (int rt = 0; rt < 4; ++rt) {
        const int row = rt * 16 + lrow, swz = (row & 7) << 4;
        const char* hb = sm + OFF_H0 + row * 256;
        f32x4 acc = {0.f, 0.f, 0.f, 0.f};
#pragma unroll
        for (int kk = 0; kk < 4; ++kk)
          acc = MFMA(w1f[kk], *(const bf16x8*)(hb + ((kk * 64 + cg * 16) ^ swz)), acc);
        f32x4 h;
#pragma unroll
        for (int q = 0; q < 4; ++q) h[q] = fmaxf(acc[q] + bb1[q], 0.f);
        *(unsigned long long*)(sm + OFF_A + row * 384 + ((wave * 32 + cg * 8) ^ swz)) = pk4(h);
      }
    }
    __syncthreads();  // (d) H1 ready (H0/O region now free)
    // ---------------- L2p: H1 -> acc + bias, LN partials ----------------
    f32x4 accE[2];
    {
      const f32x4 bb2 = *(const f32x4*)(PAR + 256 + cg2 * 16 + cg * 4);
#pragma unroll
      for (int j = 0; j < 2; ++j) {
        const int rt = rg * 2 + j, row = rt * 16 + lrow, swz = (row & 7) << 4;
        const char* hb = sm + OFF_A + row * 384;
        f32x4 acc = {0.f, 0.f, 0.f, 0.f};
#pragma unroll
        for (int kk = 0; kk < 4; ++kk)
          acc = MFMA(w2f[kk], *(const bf16x8*)(hb + ((kk * 64 + cg * 16) ^ swz)), acc);
#pragma unroll
        for (int q = 0; q < 4; ++q) acc[q] += bb2[q];
        float s = acc[0] + acc[1] + acc[2] + acc[3];
        float ss = acc[0] * acc[0] + acc[1] * acc[1] + acc[2] * acc[2] + acc[3] * acc[3];
        s += __shfl_xor(s, 16, 64); s += __shfl_xor(s, 32, 64);
        ss += __shfl_xor(ss, 16, 64); ss += __shfl_xor(ss, 32, 64);
        if (cg == 0) *(float2*)(sm + OFF_P + row * 32 + cg2 * 8) = make_float2(s, ss);
        accE[j] = acc;
      }
    }
    __syncthreads();  // (e) partials ready
    // ---------------- E2: LN + residual -> O (fp32, swizzled) ----------------
    {
      const f32x4 gv = *(const f32x4*)(PAR + 320 + cg2 * 16 + cg * 4);
      const f32x4 bv = *(const f32x4*)(PAR + 384 + cg2 * 16 + cg * 4);
#pragma unroll
      for (int j = 0; j < 2; ++j) {
        const int rt = rg * 2 + j, row = rt * 16 + lrow;
        float4 p0 = *(const float4*)(sm + OFF_P + row * 32);
        float4 p1 = *(const float4*)(sm + OFF_P + row * 32 + 16);
        float s = p0.x + p0.z + p1.x + p1.z, ss = p0.y + p0.w + p1.y + p1.w;
        float mean = s * (1.f / 64.f);
        float var = fmaxf(ss * (1.f / 64.f) - mean * mean, 0.f);
        float inv = rsqrtf(var + 1e-5f);
        const int swz = (row & 7) << 4;
        unsigned long long rv =
            *(const unsigned long long*)(sm + OFF_A + row * 384 + ((256 + cg2 * 32 + cg * 8) ^ swz));
        f32x4 a = accE[j];
        f32x4 o;
        o[0] = (a[0] - mean) * inv * gv[0] + bv[0] + bf2f((unsigned short)rv);
        o[1] = (a[1] - mean) * inv * gv[1] + bv[1] + bf2f((unsigned short)(rv >> 16));
        o[2] = (a[2] - mean) * inv * gv[2] + bv[2] + bf2f((unsigned short)(rv >> 32));
        o[3] = (a[3] - mean) * inv * gv[3] + bv[3] + bf2f((unsigned short)(rv >> 48));
        *(f32x4*)(sm + OFF_O + row * 256 + ((cg2 * 64 + cg * 16) ^ ((row & 15) << 4))) = o;
      }
    }
    __syncthreads();  // (f) O ready
    // ---------------- WR: coalesced stores + atomics ----------------
#pragma unroll
    for (int j = 0; j < 2; ++j) {
      const int row = wave * 8 + j * 4 + cg, gr = t * 64 + row;
      const int cq = lrow;
      const bool ok = EDGE || gr < M;
      f32x4 v = *(const f32x4*)(sm + OFF_O + row * 256 + ((cq * 16) ^ ((row & 15) << 4)));
      if (ok) *(f32x4*)(outp + (size_t)gr * 64 + cq * 4) = v;
      if (EDGE) {
        const int d = ((const int*)(sm + OFF_IX))[row];
        float* ap = agg + (size_t)d * 64;
#pragma unroll
        for (int k = 0; k < 4; ++k) {
          float sv = *(const float*)(sm + OFF_O + row * 256 + (((cq + k * 16) * 4) ^ ((row & 15) << 4)));
          atomicAdd(ap + cq + k * 16, sv);
        }
      }
    }
  }
}

// ---- prep: transpose+cast weights to bf16 [out][in]; rotate upd-W0 rows by 64
//      (node concat stored as [aggm|aggw|x] so x lands in the DMA segment) ----
struct PrepArgs { const float* w[9]; unsigned short* wt[3]; };

__global__ void prep_w(PrepArgs pa) {
  int i = blockIdx.x * 256 + threadIdx.x;
  if (i >= 3 * 49152) return;
  int mlp = i / 49152;
  int rem = i - mlp * 49152;
  int mat, off, K, N;
  if (rem < 24576)      { mat = 0; off = 0;     K = 192; N = 128; }
  else if (rem < 40960) { mat = 1; off = 24576; K = 128; N = 128; }
  else                  { mat = 2; off = 40960; K = 128; N = 64;  }
  int local = rem - off;
  int n = local / K, k = local - n * K;
  if (mlp == 2 && mat == 0) k = (k + 64) % 192;  // concat rotation for node MLP
  pa.wt[mlp][rem] = f2bf(pa.w[mlp * 3 + mat][k * N + n]);
}

__global__ void zero_f4(float4* p, int n) {
  int i = blockIdx.x * blockDim.x + threadIdx.x;
  if (i < n) p[i] = make_float4(0.f, 0.f, 0.f, 0.f);
}

extern "C" void kernel_launch(void* const* d_in, const int* in_sizes, int n_in,
                              void* d_out, int out_size, void* d_ws, size_t ws_size,
                              hipStream_t stream) {
  const float* x      = (const float*)d_in[0];
  const int*   meIdx  = (const int*)d_in[1];
  const float* meAttr = (const float*)d_in[2];
  const int*   weIdx  = (const int*)d_in[3];
  const float* weAttr = (const float*)d_in[4];

  float* out_x  = (float*)d_out;
  float* out_em = out_x + (size_t)NNODES * 64;
  float* out_ew = out_em + (size_t)NEDGES * 64;

  char* ws = (char*)d_ws;
  unsigned short* WtM = (unsigned short*)ws;
  unsigned short* WtW = (unsigned short*)(ws + 98304);
  unsigned short* WtU = (unsigned short*)(ws + 196608);
  float* aggm = (float*)(ws + 294912);
  float* aggw = aggm + (size_t)NNODES * 64;

  zero_f4<<<dim3(6250), dim3(256), 0, stream>>>((float4*)aggm, 1600000);

  PrepArgs pa;
  for (int m = 0; m < 3; ++m)
    for (int l = 0; l < 3; ++l)
      pa.w[m * 3 + l] = (const float*)d_in[5 + m * 8 + l * 2];
  pa.wt[0] = WtM; pa.wt[1] = WtW; pa.wt[2] = WtU;
  prep_w<<<dim3(576), dim3(256), 0, stream>>>(pa);

  // mesh edges: src = row0, dst = row1; x_i = x[dst], x_j = x[src]
  mlp_block<true><<<dim3(NBLK), dim3(512), 0, stream>>>(
      x, x, meAttr, meIdx, meIdx + NEDGES, WtM,
      (const float*)d_in[6], (const float*)d_in[8], (const float*)d_in[10],
      (const float*)d_in[11], (const float*)d_in[12],
      out_em, aggm, NEDGES);
  // world edges
  mlp_block<true><<<dim3(NBLK), dim3(512), 0, stream>>>(
      x, x, weAttr, weIdx, weIdx + NEDGES, WtW,
      (const float*)d_in[14], (const float*)d_in[16], (const float*)d_in[18],
      (const float*)d_in[19], (const float*)d_in[20],
      out_ew, aggw, NEDGES);
  // node update: A = [aggm | aggw | x], residual = x
  mlp_block<false><<<dim3(NBLK), dim3(512), 0, stream>>>(
      aggm, aggw, x, nullptr, nullptr, WtU,
      (const float*)d_in[22], (const float*)d_in[24], (const float*)d_in[26],
      (const float*)d_in[27], (const float*)d_in[28],
      out_x, nullptr, NNODES);
}